// Round 5
// baseline (16588.756 us; speedup 1.0000x reference)
//
#include <hip/hip_runtime.h>
#include <stdint.h>

typedef __attribute__((ext_vector_type(4))) int   i32x4;
typedef __attribute__((ext_vector_type(4))) float f32x4;

static constexpr int BB = 256, TT = 64, NIN = 700, NKP = 768, HH = 2048, OO = 20;
static constexpr float THRESH_V = 0.3f;

// ---------------- ws layout (bytes) ----------------
static constexpr size_t OFF_HMEM  = 0;           // 256*2048*4 = 2,097,152
static constexpr size_t OFF_SPK0  = 2097152;     // 256*2048*1 = 524,288 (i8)
static constexpr size_t OFF_OMEM  = 2621440;     // 256*20*4
static constexpr size_t OFF_OSPK  = 2641920;
static constexpr size_t OFF_OSUM  = 2662400;
static constexpr size_t ZERO_END  = 2682880;     // memset [0, ZERO_END)
static constexpr size_t OFF_SPK1  = 2682880;     // 524,288
static constexpr size_t OFF_ALPHA = 3207168;     // 256 (pad)
static constexpr size_t OFF_WHHD  = 3207424;     // 4 planes x 2048*2048 i8
static constexpr size_t WHH_PLANE = 4194304;
static constexpr size_t OFF_WIHD  = 19984640;    // 4 planes x 2048*768 i8
static constexpr size_t WIH_PLANE = 1572864;
static constexpr size_t OFF_XD    = 26276096;    // 4 planes x 64*256*768 i8
static constexpr size_t XD_PLANE  = 12582912;
static constexpr size_t WS_NEED   = 76607744;    // ~73 MB (round-3's 102 MB ran OK)

// ---------------- digit helpers ----------------
// q = rint(w*scale) computed in f64 (exact product: f32 mantissa * pow2), then
// 4 signed radix-256 digits: q = d0 + d1*2^8 + d2*2^16 + d3*2^24, d in [-128,127].
__device__ __forceinline__ void wdig(float w, double scale, signed char d[4]) {
    int q = (int)rint((double)w * scale);
    int t0 = (int)(signed char)(q & 0xFF); q = (q - t0) >> 8;
    int t1 = (int)(signed char)(q & 0xFF); q = (q - t1) >> 8;
    int t2 = (int)(signed char)(q & 0xFF); q = (q - t2) >> 8;
    d[0] = (signed char)t0; d[1] = (signed char)t1;
    d[2] = (signed char)t2; d[3] = (signed char)q;
}

// swizzled LDS 16B fragment read: tile [64 rows][128 bytes], slot = 16B unit,
// XOR'd by (row&7) so ds_read_b128 across 16 rows is bank-conflict-free.
__device__ __forceinline__ i32x4 ldf8(const uint8_t* lds, int row, int slot) {
    return *reinterpret_cast<const i32x4*>(lds + row * 128 + ((slot ^ (row & 7)) << 4));
}

// stage one [64 rows][128B] tile global->LDS via global_load_lds dwordx4.
// LDS dest linear (wave-uniform base + lane*16B); global source pre-swizzled
// with the same XOR so ldf8() reads are correct (both-sides rule).
__device__ __forceinline__ void stageB(const uint8_t* g, int rbase, int strideB, int k0B,
                                       uint8_t* lds, int wid, int lane) {
#pragma unroll
    for (int q = 0; q < 2; ++q) {
        int c    = q * 4 + wid;          // chunk 0..7, 1KB each
        int row  = c * 8 + (lane >> 3);  // 0..63
        int slot = lane & 7;
        const uint8_t* src = g + (size_t)(rbase + row) * strideB + k0B + ((slot ^ (row & 7)) << 4);
        __builtin_amdgcn_global_load_lds((const __attribute__((address_space(1))) void*)src,
                                         (__attribute__((address_space(3))) void*)(lds + c * 1024),
                                         16, 0, 0);
    }
}

// ---------------- conversion kernels ----------------
__global__ __launch_bounds__(256) void conv_whh_i8(const float* __restrict__ W,
                                                   int8_t* __restrict__ p0, int8_t* __restrict__ p1,
                                                   int8_t* __restrict__ p2, int8_t* __restrict__ p3,
                                                   const float* __restrict__ tau_h,
                                                   const float* __restrict__ tau_o,
                                                   float* __restrict__ alpha) {
    int idx = blockIdx.x * 256 + threadIdx.x;   // quads over 2048*2048
    if (idx == 0) {
        // mimic np: q = -1.0f/tau (f32), alpha = exp(q) (correctly-rounded via f64)
        float qh = __fdiv_rn(-1.0f, tau_h[0]);
        float qo = __fdiv_rn(-1.0f, tau_o[0]);
        alpha[0] = (float)exp((double)qh);
        alpha[1] = (float)exp((double)qo);
    }
    float4 v = reinterpret_cast<const float4*>(W)[idx];
    signed char dx[4], dy[4], dz[4], dw[4];
    const double SC = 1073741824.0;  // 2^30; |W_hh| < 0.2 -> |q| < 2^28
    wdig(v.x, SC, dx); wdig(v.y, SC, dy); wdig(v.z, SC, dz); wdig(v.w, SC, dw);
    reinterpret_cast<char4*>(p0)[idx] = make_char4(dx[0], dy[0], dz[0], dw[0]);
    reinterpret_cast<char4*>(p1)[idx] = make_char4(dx[1], dy[1], dz[1], dw[1]);
    reinterpret_cast<char4*>(p2)[idx] = make_char4(dx[2], dy[2], dz[2], dw[2]);
    reinterpret_cast<char4*>(p3)[idx] = make_char4(dx[3], dy[3], dz[3], dw[3]);
}

__global__ __launch_bounds__(256) void conv_wih_i8(const float* __restrict__ W,
                                                   int8_t* __restrict__ p0, int8_t* __restrict__ p1,
                                                   int8_t* __restrict__ p2, int8_t* __restrict__ p3) {
    int row = blockIdx.x;   // 0..2047
    for (int i = threadIdx.x; i < NKP; i += 256) {
        float v = (i < NIN) ? W[(size_t)row * NIN + i] : 0.f;
        signed char d[4];
        wdig(v, 1073741824.0, d);        // 2^30
        size_t o = (size_t)row * NKP + i;
        p0[o] = d[0]; p1[o] = d[1]; p2[o] = d[2]; p3[o] = d[3];
    }
}

__global__ __launch_bounds__(256) void conv_x_i8(const float* __restrict__ in,
                                                 int8_t* __restrict__ p0, int8_t* __restrict__ p1,
                                                 int8_t* __restrict__ p2, int8_t* __restrict__ p3) {
    int blk = blockIdx.x;                 // 64*256
    int t = blk >> 8, b = blk & 255;
    const float* src = in + ((size_t)b * TT + t) * NIN;   // input [B,T,N]
    size_t dst = ((size_t)t * BB + b) * NKP;              // digits [T,B,NKP]
    for (int i = threadIdx.x; i < NKP; i += 256) {
        float v = (i < NIN) ? src[i] : 0.f;
        signed char d[4];
        wdig(v, 16777216.0, d);          // 2^24; x in [0,1) -> q in [0, 2^24]
        p0[dst + i] = d[0]; p1[dst + i] = d[1]; p2[dst + i] = d[2]; p3[dst + i] = d[3];
    }
}

// ---------------- output-LIF update (exact f64 dot over 0/1 spikes) ----------------
__device__ __forceinline__ void o_update(int owg, int tid, const int8_t* __restrict__ spk,
                                         const float* __restrict__ W_ho, const float* __restrict__ b_ho,
                                         float a_o, float* __restrict__ o_mem,
                                         float* __restrict__ o_spk, float* __restrict__ o_sum,
                                         float* __restrict__ out /*nullptr unless final*/) {
    for (int c = tid; c < 32 * OO; c += 256) {
        int b = owg * 32 + c / OO;
        int o = c % OO;
        const int8_t* srow = spk  + (size_t)b * HH;
        const float*  wrow = W_ho + (size_t)o * HH;
        double acc = 0.0;
        for (int k = 0; k < HH; k += 4) {
            int s4 = *reinterpret_cast<const int*>(srow + k);
            float4 wv = *reinterpret_cast<const float4*>(wrow + k);
            if (s4 & 0x000000FF) acc += (double)wv.x;
            if (s4 & 0x0000FF00) acc += (double)wv.y;
            if (s4 & 0x00FF0000) acc += (double)wv.z;
            if (s4 & 0xFF000000) acc += (double)wv.w;
        }
        float dot = (float)acc;
        size_t oo = (size_t)b * OO + o;
        float om = o_mem[oo], osp = o_spk[oo];
        // np order: ((o_mem*alpha)*(1-o_spike) + dot) + b_ho
        float v = __fadd_rn(__fadd_rn(__fmul_rn(__fmul_rn(om, a_o), 1.f - osp), dot), b_ho[o]);
        float sn = (v > THRESH_V) ? 1.f : 0.f;
        o_mem[oo] = v;
        o_spk[oo] = sn;
        float s = __fadd_rn(o_sum[oo], sn);
        o_sum[oo] = s;
        if (out) out[oo] = __fmul_rn(s, 1.f / 64.f);   // /64 exact
    }
}

// ---------------- per-step fused kernel ----------------
__global__ __launch_bounds__(256) void step_kernel(
    const int8_t* __restrict__ whhd,   // 4 planes, stride WHH_PLANE
    const int8_t* __restrict__ wihd,   // 4 planes, stride WIH_PLANE
    const int8_t* __restrict__ xd,     // 4 planes, stride XD_PLANE
    const int8_t* __restrict__ spk_rd, int8_t* __restrict__ spk_wr,
    float* __restrict__ h_mem, const float* __restrict__ alpha,
    const float* __restrict__ b_ih, const float* __restrict__ b_hh,
    const float* __restrict__ W_ho, const float* __restrict__ b_ho,
    float* __restrict__ o_mem, float* __restrict__ o_spk, float* __restrict__ o_sum,
    int t) {
    __shared__ __align__(16) uint8_t At[4][8192];   // [64 rows][128B] tiles
    __shared__ __align__(16) uint8_t Bt[4][8192];

    int bid = blockIdx.x;
    int tid = threadIdx.x;

    if (bid < 128) {
        int lane = tid & 63, wid = tid >> 6;
        int m0 = (bid >> 5) * 64;      // batch tile
        int n0 = (bid & 31) * 64;      // hidden tile
        int wr = (wid >> 1) * 32, wc = (wid & 1) * 32;
        int fr = lane & 15, hi4 = lane >> 4;

        // ===== recurrent segment: exact i8, spikes @ Whh digits, K=2048 =====
        i32x4 aR[4][2][2] = {};
        for (int kt = 0; kt < 16; ++kt) {
            int k0B = kt * 128;
            stageB((const uint8_t*)spk_rd, m0, HH, k0B, At[0], wid, lane);
#pragma unroll
            for (int b = 0; b < 4; ++b)
                stageB((const uint8_t*)(whhd + (size_t)b * WHH_PLANE), n0, HH, k0B, Bt[b], wid, lane);
            __syncthreads();
#pragma unroll
            for (int ks = 0; ks < 2; ++ks) {
                int sl = ks * 4 + hi4;
                i32x4 a0 = ldf8(At[0], wr + fr,      sl);
                i32x4 a1 = ldf8(At[0], wr + 16 + fr, sl);
#pragma unroll
                for (int b = 0; b < 4; ++b) {
                    i32x4 b0 = ldf8(Bt[b], wc + fr,      sl);
                    i32x4 b1 = ldf8(Bt[b], wc + 16 + fr, sl);
                    aR[b][0][0] = __builtin_amdgcn_mfma_i32_16x16x64_i8(a0, b0, aR[b][0][0], 0, 0, 0);
                    aR[b][0][1] = __builtin_amdgcn_mfma_i32_16x16x64_i8(a0, b1, aR[b][0][1], 0, 0, 0);
                    aR[b][1][0] = __builtin_amdgcn_mfma_i32_16x16x64_i8(a1, b0, aR[b][1][0], 0, 0, 0);
                    aR[b][1][1] = __builtin_amdgcn_mfma_i32_16x16x64_i8(a1, b1, aR[b][1][1], 0, 0, 0);
                }
            }
            __syncthreads();
        }
        // combine digits -> f32 rec (single rounding; exact vs real-valued dot to ~1e-8)
        f32x4 recf[2][2];
#pragma unroll
        for (int m = 0; m < 2; ++m)
#pragma unroll
            for (int n = 0; n < 2; ++n)
#pragma unroll
                for (int r = 0; r < 4; ++r)
                    recf[m][n][r] = (float)((double)aR[3][m][n][r] * 0x1p-6
                                          + (double)aR[2][m][n][r] * 0x1p-14
                                          + (double)aR[1][m][n][r] * 0x1p-22
                                          + (double)aR[0][m][n][r] * 0x1p-30);

        // ===== input-projection segment: exact i8 digit pairs (a+b>=2), K=768 =====
        i32x4 aX[5][2][2] = {};   // grouped by c=a+b-2 in 0..4
        const uint8_t* xbase = (const uint8_t*)xd + (size_t)t * BB * NKP;
        for (int kt = 0; kt < 6; ++kt) {
            int k0B = kt * 128;
#pragma unroll
            for (int a = 0; a < 4; ++a)
                stageB(xbase + (size_t)a * XD_PLANE, m0, NKP, k0B, At[a], wid, lane);
#pragma unroll
            for (int b = 0; b < 4; ++b)
                stageB((const uint8_t*)(wihd + (size_t)b * WIH_PLANE), n0, NKP, k0B, Bt[b], wid, lane);
            __syncthreads();
#pragma unroll
            for (int ks = 0; ks < 2; ++ks) {
                int sl = ks * 4 + hi4;
                i32x4 fa[4][2], fb[4][2];
#pragma unroll
                for (int a = 0; a < 4; ++a) {
                    fa[a][0] = ldf8(At[a], wr + fr,      sl);
                    fa[a][1] = ldf8(At[a], wr + 16 + fr, sl);
                    fb[a][0] = ldf8(Bt[a], wc + fr,      sl);
                    fb[a][1] = ldf8(Bt[a], wc + 16 + fr, sl);
                }
#pragma unroll
                for (int a = 0; a < 4; ++a)
#pragma unroll
                    for (int b = 0; b < 4; ++b) {
                        if (a + b < 2) continue;   // dropped terms ~2e-9 rms
                        const int c = a + b - 2;
#pragma unroll
                        for (int m = 0; m < 2; ++m)
#pragma unroll
                            for (int n = 0; n < 2; ++n)
                                aX[c][m][n] = __builtin_amdgcn_mfma_i32_16x16x64_i8(
                                    fa[a][m], fb[b][n], aX[c][m][n], 0, 0, 0);
                    }
            }
            __syncthreads();
        }

        // ===== epilogue: LIF update in np's exact op order =====
        float a_h = alpha[0];
        int lr = (lane >> 4) * 4, lc = lane & 15;
#pragma unroll
        for (int m = 0; m < 2; ++m)
#pragma unroll
            for (int n = 0; n < 2; ++n)
#pragma unroll
                for (int r = 0; r < 4; ++r) {
                    int b = m0 + wr + m * 16 + lr + r;
                    int j = n0 + wc + n * 16 + lc;
                    size_t off = (size_t)b * HH + j;
                    // einsum value: sum_c S_c * 2^(8(c+2)-54), exact f64 combine
                    double xp64 = (double)aX[4][m][n][r] * 0x1p-6
                                + (double)aX[3][m][n][r] * 0x1p-14
                                + (double)aX[2][m][n][r] * 0x1p-22
                                + (double)aX[1][m][n][r] * 0x1p-30
                                + (double)aX[0][m][n][r] * 0x1p-38;
                    float xpf = (float)xp64;
                    float xpb = __fadd_rn(xpf, b_ih[j]);          // x_proj = einsum + b_ih
                    float hv = h_mem[off];
                    float keep = spk_rd[off] ? 0.f : 1.f;         // (1 - s_prev), exact
                    // np: ((h*alpha)*(1-s) + x_proj) + rec + b_hh, left-to-right, no FMA
                    float v = __fadd_rn(__fmul_rn(__fmul_rn(hv, a_h), keep), xpb);
                    v = __fadd_rn(v, recf[m][n][r]);
                    v = __fadd_rn(v, b_hh[j]);
                    h_mem[off] = v;
                    spk_wr[off] = (v > THRESH_V) ? (int8_t)1 : (int8_t)0;
                }
    } else {
        if (t == 0) return;            // no step-(t-1) spikes yet
        o_update(bid - 128, tid, spk_rd, W_ho, b_ho, alpha[1], o_mem, o_spk, o_sum, nullptr);
    }
}

__global__ __launch_bounds__(256) void final_kernel(const int8_t* __restrict__ spk,
                                                    const float* __restrict__ W_ho,
                                                    const float* __restrict__ b_ho,
                                                    const float* __restrict__ alpha,
                                                    float* __restrict__ o_mem,
                                                    float* __restrict__ o_spk,
                                                    float* __restrict__ o_sum,
                                                    float* __restrict__ out) {
    o_update(blockIdx.x, threadIdx.x, spk, W_ho, b_ho, alpha[1], o_mem, o_spk, o_sum, out);
}

// ---------------- host ----------------
extern "C" void kernel_launch(void* const* d_in, const int* in_sizes, int n_in,
                              void* d_out, int out_size, void* d_ws, size_t ws_size,
                              hipStream_t stream) {
    const float* in    = (const float*)d_in[0];
    const float* W_ih  = (const float*)d_in[1];
    const float* b_ih  = (const float*)d_in[2];
    const float* W_hh  = (const float*)d_in[3];
    const float* b_hh  = (const float*)d_in[4];
    const float* W_ho  = (const float*)d_in[5];
    const float* b_ho  = (const float*)d_in[6];
    const float* tau_h = (const float*)d_in[7];
    const float* tau_o = (const float*)d_in[8];

    uint8_t* ws = (uint8_t*)d_ws;
    float*  h_mem = (float*)(ws + OFF_HMEM);
    int8_t* spk0  = (int8_t*)(ws + OFF_SPK0);
    float*  o_mem = (float*)(ws + OFF_OMEM);
    float*  o_spk = (float*)(ws + OFF_OSPK);
    float*  o_sum = (float*)(ws + OFF_OSUM);
    int8_t* spk1  = (int8_t*)(ws + OFF_SPK1);
    float*  alpha = (float*)(ws + OFF_ALPHA);
    int8_t* whhd  = (int8_t*)(ws + OFF_WHHD);
    int8_t* wihd  = (int8_t*)(ws + OFF_WIHD);
    int8_t* xd    = (int8_t*)(ws + OFF_XD);

    if (ws_size < WS_NEED) return;  // insufficient scratch -> output stays zero (diagnostic)

    hipMemsetAsync(ws, 0, ZERO_END, stream);
    conv_whh_i8<<<4096, 256, 0, stream>>>(W_hh,
                                          whhd, whhd + WHH_PLANE, whhd + 2 * WHH_PLANE, whhd + 3 * WHH_PLANE,
                                          tau_h, tau_o, alpha);
    conv_wih_i8<<<2048, 256, 0, stream>>>(W_ih,
                                          wihd, wihd + WIH_PLANE, wihd + 2 * WIH_PLANE, wihd + 3 * WIH_PLANE);
    conv_x_i8<<<16384, 256, 0, stream>>>(in,
                                         xd, xd + XD_PLANE, xd + 2 * XD_PLANE, xd + 3 * XD_PLANE);

    for (int t = 0; t < TT; ++t) {
        const int8_t* srd = (t & 1) ? spk1 : spk0;
        int8_t*       swr = (t & 1) ? spk0 : spk1;
        step_kernel<<<136, 256, 0, stream>>>(whhd, wihd, xd, srd, swr, h_mem, alpha,
                                             b_ih, b_hh, W_ho, b_ho, o_mem, o_spk, o_sum, t);
    }
    // step 63's output update + final normalization (spikes of step 63 are in spk0)
    final_kernel<<<8, 256, 0, stream>>>(spk0, W_ho, b_ho, alpha, o_mem, o_spk, o_sum,
                                        (float*)d_out);
}

// Round 6
// 5031.435 us; speedup vs baseline: 3.2970x; 3.2970x over previous
//
#include <hip/hip_runtime.h>
#include <stdint.h>

typedef __attribute__((ext_vector_type(4))) int   i32x4;

static constexpr int BB = 256, TT = 64, NIN = 700, NKP = 768, HH = 2048, OO = 20;
static constexpr float THRESH_V = 0.3f;
static constexpr int NGEMM = 512;   // 8 m-tiles (M32) x 64 n-tiles (N32); bid = m*64+n -> same-n on same XCD
static constexpr int NOBLK = 20;    // 20 blocks x 256 threads = 5120 = BB*OO output dots

// ---------------- ws layout (bytes) ---- unchanged from validated round-4 ----
static constexpr size_t OFF_HMEM  = 0;           // 256*2048*4
static constexpr size_t OFF_SPK0  = 2097152;     // 256*2048*1 (i8)
static constexpr size_t OFF_OMEM  = 2621440;
static constexpr size_t OFF_OSPK  = 2641920;
static constexpr size_t OFF_OSUM  = 2662400;
static constexpr size_t ZERO_END  = 2682880;
static constexpr size_t OFF_SPK1  = 2682880;
static constexpr size_t OFF_ALPHA = 3207168;
static constexpr size_t OFF_WHHD  = 3207424;     // 4 planes x 2048*2048 i8
static constexpr size_t WHH_PLANE = 4194304;
static constexpr size_t OFF_WIHD  = 19984640;    // 4 planes x 2048*768 i8
static constexpr size_t WIH_PLANE = 1572864;
static constexpr size_t OFF_XD    = 26276096;    // 4 planes x 64*256*768 i8
static constexpr size_t XD_PLANE  = 12582912;
static constexpr size_t WS_NEED   = 76607744;    // known-OK (round 4/5 ran)

// ---------------- sync macros (m201-verified pattern) ----------------
#define WAIT_VM5() asm volatile("s_waitcnt vmcnt(5)" ::: "memory")
#define WAIT_VM8() asm volatile("s_waitcnt vmcnt(8)" ::: "memory")
#define WAIT_VM0() asm volatile("s_waitcnt vmcnt(0)" ::: "memory")
#define SCHED0()   __builtin_amdgcn_sched_barrier(0)
#define BARRIER()  asm volatile("s_barrier" ::: "memory")

// ---------------- digit helpers (identical to validated round 4) ----------------
__device__ __forceinline__ void wdig(float w, double scale, signed char d[4]) {
    int q = (int)rint((double)w * scale);
    int t0 = (int)(signed char)(q & 0xFF); q = (q - t0) >> 8;
    int t1 = (int)(signed char)(q & 0xFF); q = (q - t1) >> 8;
    int t2 = (int)(signed char)(q & 0xFF); q = (q - t2) >> 8;
    d[0] = (signed char)t0; d[1] = (signed char)t1;
    d[2] = (signed char)t2; d[3] = (signed char)q;
}

// swizzled LDS 16B fragment read: tile [32 rows][128 bytes], slot XOR'd by (row&7)
__device__ __forceinline__ i32x4 ldf8(const uint8_t* lds, int row, int slot) {
    return *reinterpret_cast<const i32x4*>(lds + row * 128 + ((slot ^ (row & 7)) << 4));
}

// stage a [32 rows][128B] tile global->LDS; exactly ONE global_load_lds per wave.
// LDS dest linear (wave-uniform base + lane*16B); global source pre-swizzled (both-sides rule).
__device__ __forceinline__ void stage32(const uint8_t* g, int rbase, int strideB, int k0B,
                                        uint8_t* ldsT, int wid, int lane) {
    int row  = wid * 8 + (lane >> 3);    // wave wid covers rows 8w..8w+7
    int slot = lane & 7;
    const uint8_t* src = g + (size_t)(rbase + row) * strideB + k0B + ((slot ^ (row & 7)) << 4);
    __builtin_amdgcn_global_load_lds((const __attribute__((address_space(1))) void*)src,
                                     (__attribute__((address_space(3))) void*)(ldsT + wid * 1024),
                                     16, 0, 0);
}

// buffer layout: A planes at p*4096 (rec uses p=0), B planes at 16384+p*4096; buffer = 32KB
__device__ __forceinline__ void stage_rec(uint8_t* buf, const int8_t* spk, const int8_t* whhd,
                                          int m0, int n0, int k0B, int wid, int lane) {
    stage32((const uint8_t*)spk, m0, HH, k0B, buf, wid, lane);                 // 1 load/wave
#pragma unroll
    for (int p = 0; p < 4; ++p)                                               // 4 loads/wave
        stage32((const uint8_t*)(whhd + (size_t)p * WHH_PLANE), n0, HH, k0B,
                buf + 16384 + p * 4096, wid, lane);
}
__device__ __forceinline__ void stage_x(uint8_t* buf, const int8_t* xd_t, const int8_t* wihd,
                                        int m0, int n0, int k0B, int wid, int lane) {
#pragma unroll
    for (int p = 0; p < 4; ++p)                                               // 4 loads/wave
        stage32((const uint8_t*)(xd_t + (size_t)p * XD_PLANE), m0, NKP, k0B,
                buf + p * 4096, wid, lane);
#pragma unroll
    for (int p = 0; p < 4; ++p)                                               // 4 loads/wave
        stage32((const uint8_t*)(wihd + (size_t)p * WIH_PLANE), n0, NKP, k0B,
                buf + 16384 + p * 4096, wid, lane);
}

__device__ __forceinline__ void mfma_rec(const uint8_t* buf, int mw, int nw, int fr, int hi4,
                                         i32x4 aR[4]) {
#pragma unroll
    for (int ks = 0; ks < 2; ++ks) {
        int sl = ks * 4 + hi4;
        i32x4 a = ldf8(buf, mw * 16 + fr, sl);
#pragma unroll
        for (int p = 0; p < 4; ++p) {
            i32x4 b = ldf8(buf + 16384 + p * 4096, nw * 16 + fr, sl);
            aR[p] = __builtin_amdgcn_mfma_i32_16x16x64_i8(a, b, aR[p], 0, 0, 0);
        }
    }
}
__device__ __forceinline__ void mfma_x(const uint8_t* buf, int mw, int nw, int fr, int hi4,
                                       i32x4 aX[5]) {
#pragma unroll
    for (int ks = 0; ks < 2; ++ks) {
        int sl = ks * 4 + hi4;
        i32x4 fa[4], fb[4];
#pragma unroll
        for (int p = 0; p < 4; ++p) {
            fa[p] = ldf8(buf + p * 4096,         mw * 16 + fr, sl);
            fb[p] = ldf8(buf + 16384 + p * 4096, nw * 16 + fr, sl);
        }
#pragma unroll
        for (int a = 0; a < 4; ++a)
#pragma unroll
            for (int b = 0; b < 4; ++b) {
                if (a + b < 2) continue;     // dropped terms ~2e-9 rms (validated)
                const int c = a + b - 2;
                aX[c] = __builtin_amdgcn_mfma_i32_16x16x64_i8(fa[a], fb[b], aX[c], 0, 0, 0);
            }
    }
}

// ---------------- conversion kernels (unchanged, validated) ----------------
__global__ __launch_bounds__(256) void conv_whh_i8(const float* __restrict__ W,
                                                   int8_t* __restrict__ p0, int8_t* __restrict__ p1,
                                                   int8_t* __restrict__ p2, int8_t* __restrict__ p3,
                                                   const float* __restrict__ tau_h,
                                                   const float* __restrict__ tau_o,
                                                   float* __restrict__ alpha) {
    int idx = blockIdx.x * 256 + threadIdx.x;
    if (idx == 0) {
        float qh = __fdiv_rn(-1.0f, tau_h[0]);
        float qo = __fdiv_rn(-1.0f, tau_o[0]);
        alpha[0] = (float)exp((double)qh);
        alpha[1] = (float)exp((double)qo);
    }
    float4 v = reinterpret_cast<const float4*>(W)[idx];
    signed char dx[4], dy[4], dz[4], dw[4];
    const double SC = 1073741824.0;  // 2^30
    wdig(v.x, SC, dx); wdig(v.y, SC, dy); wdig(v.z, SC, dz); wdig(v.w, SC, dw);
    reinterpret_cast<char4*>(p0)[idx] = make_char4(dx[0], dy[0], dz[0], dw[0]);
    reinterpret_cast<char4*>(p1)[idx] = make_char4(dx[1], dy[1], dz[1], dw[1]);
    reinterpret_cast<char4*>(p2)[idx] = make_char4(dx[2], dy[2], dz[2], dw[2]);
    reinterpret_cast<char4*>(p3)[idx] = make_char4(dx[3], dy[3], dz[3], dw[3]);
}

__global__ __launch_bounds__(256) void conv_wih_i8(const float* __restrict__ W,
                                                   int8_t* __restrict__ p0, int8_t* __restrict__ p1,
                                                   int8_t* __restrict__ p2, int8_t* __restrict__ p3) {
    int row = blockIdx.x;
    for (int i = threadIdx.x; i < NKP; i += 256) {
        float v = (i < NIN) ? W[(size_t)row * NIN + i] : 0.f;
        signed char d[4];
        wdig(v, 1073741824.0, d);        // 2^30
        size_t o = (size_t)row * NKP + i;
        p0[o] = d[0]; p1[o] = d[1]; p2[o] = d[2]; p3[o] = d[3];
    }
}

__global__ __launch_bounds__(256) void conv_x_i8(const float* __restrict__ in,
                                                 int8_t* __restrict__ p0, int8_t* __restrict__ p1,
                                                 int8_t* __restrict__ p2, int8_t* __restrict__ p3) {
    int blk = blockIdx.x;
    int t = blk >> 8, b = blk & 255;
    const float* src = in + ((size_t)b * TT + t) * NIN;   // input [B,T,N]
    size_t dst = ((size_t)t * BB + b) * NKP;              // digits [T,B,NKP]
    for (int i = threadIdx.x; i < NKP; i += 256) {
        float v = (i < NIN) ? src[i] : 0.f;
        signed char d[4];
        wdig(v, 16777216.0, d);          // 2^24
        p0[dst + i] = d[0]; p1[dst + i] = d[1]; p2[dst + i] = d[2]; p3[dst + i] = d[3];
    }
}

// ---------------- output-LIF: one thread per (b,o) dot, branchless f64 ----------------
__device__ __forceinline__ void o_dot(int gid, const int8_t* __restrict__ spk,
                                      const float* __restrict__ W_ho, const float* __restrict__ b_ho,
                                      float a_o, float* __restrict__ o_mem,
                                      float* __restrict__ o_spk, float* __restrict__ o_sum,
                                      float* __restrict__ out /*nullptr unless final*/) {
    int b = gid / OO, o = gid % OO;
    const int8_t* srow = spk  + (size_t)b * HH;
    const float*  wrow = W_ho + (size_t)o * HH;
    double a0 = 0.0, a1 = 0.0, a2 = 0.0, a3 = 0.0;
    for (int k = 0; k < HH; k += 8) {
        int2   s  = *reinterpret_cast<const int2*>(srow + k);
        float4 w0 = *reinterpret_cast<const float4*>(wrow + k);
        float4 w1 = *reinterpret_cast<const float4*>(wrow + k + 4);
        a0 += (s.x & 0x000000FF) ? (double)w0.x : 0.0;
        a1 += (s.x & 0x0000FF00) ? (double)w0.y : 0.0;
        a2 += (s.x & 0x00FF0000) ? (double)w0.z : 0.0;
        a3 += (s.x & 0xFF000000) ? (double)w0.w : 0.0;
        a0 += (s.y & 0x000000FF) ? (double)w1.x : 0.0;
        a1 += (s.y & 0x0000FF00) ? (double)w1.y : 0.0;
        a2 += (s.y & 0x00FF0000) ? (double)w1.z : 0.0;
        a3 += (s.y & 0xFF000000) ? (double)w1.w : 0.0;
    }
    float dot = (float)((a0 + a1) + (a2 + a3));
    size_t oo = (size_t)b * OO + o;
    float om = o_mem[oo], osp = o_spk[oo];
    // np order: ((o_mem*alpha)*(1-o_spike) + dot) + b_ho
    float v = __fadd_rn(__fadd_rn(__fmul_rn(__fmul_rn(om, a_o), 1.f - osp), dot), b_ho[o]);
    float sn = (v > THRESH_V) ? 1.f : 0.f;
    o_mem[oo] = v;
    o_spk[oo] = sn;
    float s = __fadd_rn(o_sum[oo], sn);
    o_sum[oo] = s;
    if (out) out[oo] = __fmul_rn(s, 1.f / 64.f);
}

// ---------------- per-step fused kernel ----------------
__global__ __launch_bounds__(256, 2) void step_kernel(
    const int8_t* __restrict__ whhd, const int8_t* __restrict__ wihd,
    const int8_t* __restrict__ xd,
    const int8_t* __restrict__ spk_rd, int8_t* __restrict__ spk_wr,
    float* __restrict__ h_mem, const float* __restrict__ alpha,
    const float* __restrict__ b_ih, const float* __restrict__ b_hh,
    const float* __restrict__ W_ho, const float* __restrict__ b_ho,
    float* __restrict__ o_mem, float* __restrict__ o_spk, float* __restrict__ o_sum,
    int t) {
    __shared__ __align__(16) uint8_t lds[2][32768];   // double-buffered 32KB tiles

    int bid = blockIdx.x;
    int tid = threadIdx.x;

    if (bid < NGEMM) {
        int lane = tid & 63, wid = tid >> 6;
        int m0 = (bid >> 6) * 32;        // batch tile  (8 tiles)
        int n0 = (bid & 63) * 32;        // hidden tile (64 tiles; n%8 -> XCD locality)
        int mw = wid >> 1, nw = wid & 1; // wave's 16x16 frag within the 32x32 tile
        int fr = lane & 15, hi4 = lane >> 4;

        const int8_t* xd_t = xd + (size_t)t * BB * NKP;

        i32x4 aR[4] = {};   // recurrent digit accumulators
        i32x4 aX[5] = {};   // x-proj digit-pair accumulators

        // ---- software pipeline: prefetch-1 with counted vmcnt (never 0 mid-loop) ----
        stage_rec(lds[0], spk_rd, whhd, m0, n0, 0, wid, lane);          // 5/wave in flight
        for (int kt = 0; kt < 15; ++kt) {
            stage_rec(lds[(kt + 1) & 1], spk_rd, whhd, m0, n0, (kt + 1) * 128, wid, lane);
            WAIT_VM5();                       // iter-kt's 5 loads done; next 5 in flight
            SCHED0();
            BARRIER();
            mfma_rec(lds[kt & 1], mw, nw, fr, hi4, aR);
            SCHED0();
            BARRIER();                        // protect buf[kt&1] before overwrite
        }
        // kt=15: prefetch x iter 0 into lds[0]
        stage_x(lds[0], xd_t, wihd, m0, n0, 0, wid, lane);
        WAIT_VM8();
        SCHED0();
        BARRIER();
        mfma_rec(lds[1], mw, nw, fr, hi4, aR);
        SCHED0();
        BARRIER();
        for (int j = 0; j < 5; ++j) {
            stage_x(lds[(j + 1) & 1], xd_t, wihd, m0, n0, (j + 1) * 128, wid, lane);
            WAIT_VM8();
            SCHED0();
            BARRIER();
            mfma_x(lds[j & 1], mw, nw, fr, hi4, aX);
            SCHED0();
            BARRIER();
        }
        WAIT_VM0();
        SCHED0();
        BARRIER();
        mfma_x(lds[1], mw, nw, fr, hi4, aX);

        // ---- epilogue: LIF update, np's exact op order (identical to round 4) ----
        float a_h = alpha[0];
        int j = n0 + nw * 16 + fr;
        int rq = hi4 * 4;
#pragma unroll
        for (int r = 0; r < 4; ++r) {
            int b = m0 + mw * 16 + rq + r;
            size_t off = (size_t)b * HH + j;
            float recf = (float)((double)aR[3][r] * 0x1p-6
                               + (double)aR[2][r] * 0x1p-14
                               + (double)aR[1][r] * 0x1p-22
                               + (double)aR[0][r] * 0x1p-30);
            double xp64 = (double)aX[4][r] * 0x1p-6
                        + (double)aX[3][r] * 0x1p-14
                        + (double)aX[2][r] * 0x1p-22
                        + (double)aX[1][r] * 0x1p-30
                        + (double)aX[0][r] * 0x1p-38;
            float xpf = (float)xp64;
            float xpb = __fadd_rn(xpf, b_ih[j]);
            float hv  = h_mem[off];
            float keep = spk_rd[off] ? 0.f : 1.f;
            float v = __fadd_rn(__fmul_rn(__fmul_rn(hv, a_h), keep), xpb);
            v = __fadd_rn(v, recf);
            v = __fadd_rn(v, b_hh[j]);
            h_mem[off] = v;
            spk_wr[off] = (v > THRESH_V) ? (int8_t)1 : (int8_t)0;
        }
    } else {
        if (t == 0) return;              // no step-(t-1) spikes yet
        int gid = (bid - NGEMM) * 256 + tid;   // 0..5119
        o_dot(gid, spk_rd, W_ho, b_ho, alpha[1], o_mem, o_spk, o_sum, nullptr);
    }
}

__global__ __launch_bounds__(256) void final_kernel(const int8_t* __restrict__ spk,
                                                    const float* __restrict__ W_ho,
                                                    const float* __restrict__ b_ho,
                                                    const float* __restrict__ alpha,
                                                    float* __restrict__ o_mem,
                                                    float* __restrict__ o_spk,
                                                    float* __restrict__ o_sum,
                                                    float* __restrict__ out) {
    int gid = blockIdx.x * 256 + threadIdx.x;
    o_dot(gid, spk, W_ho, b_ho, alpha[1], o_mem, o_spk, o_sum, out);
}

// ---------------- host ----------------
extern "C" void kernel_launch(void* const* d_in, const int* in_sizes, int n_in,
                              void* d_out, int out_size, void* d_ws, size_t ws_size,
                              hipStream_t stream) {
    const float* in    = (const float*)d_in[0];
    const float* W_ih  = (const float*)d_in[1];
    const float* b_ih  = (const float*)d_in[2];
    const float* W_hh  = (const float*)d_in[3];
    const float* b_hh  = (const float*)d_in[4];
    const float* W_ho  = (const float*)d_in[5];
    const float* b_ho  = (const float*)d_in[6];
    const float* tau_h = (const float*)d_in[7];
    const float* tau_o = (const float*)d_in[8];

    uint8_t* ws = (uint8_t*)d_ws;
    float*  h_mem = (float*)(ws + OFF_HMEM);
    int8_t* spk0  = (int8_t*)(ws + OFF_SPK0);
    float*  o_mem = (float*)(ws + OFF_OMEM);
    float*  o_spk = (float*)(ws + OFF_OSPK);
    float*  o_sum = (float*)(ws + OFF_OSUM);
    int8_t* spk1  = (int8_t*)(ws + OFF_SPK1);
    float*  alpha = (float*)(ws + OFF_ALPHA);
    int8_t* whhd  = (int8_t*)(ws + OFF_WHHD);
    int8_t* wihd  = (int8_t*)(ws + OFF_WIHD);
    int8_t* xd    = (int8_t*)(ws + OFF_XD);

    if (ws_size < WS_NEED) return;

    hipMemsetAsync(ws, 0, ZERO_END, stream);
    conv_whh_i8<<<4096, 256, 0, stream>>>(W_hh,
                                          whhd, whhd + WHH_PLANE, whhd + 2 * WHH_PLANE, whhd + 3 * WHH_PLANE,
                                          tau_h, tau_o, alpha);
    conv_wih_i8<<<2048, 256, 0, stream>>>(W_ih,
                                          wihd, wihd + WIH_PLANE, wihd + 2 * WIH_PLANE, wihd + 3 * WIH_PLANE);
    conv_x_i8<<<16384, 256, 0, stream>>>(in,
                                         xd, xd + XD_PLANE, xd + 2 * XD_PLANE, xd + 3 * XD_PLANE);

    for (int t = 0; t < TT; ++t) {
        const int8_t* srd = (t & 1) ? spk1 : spk0;
        int8_t*       swr = (t & 1) ? spk0 : spk1;
        step_kernel<<<NGEMM + NOBLK, 256, 0, stream>>>(whhd, wihd, xd, srd, swr, h_mem, alpha,
                                                       b_ih, b_hh, W_ho, b_ho,
                                                       o_mem, o_spk, o_sum, t);
    }
    final_kernel<<<NOBLK, 256, 0, stream>>>(spk0, W_ho, b_ho, alpha, o_mem, o_spk, o_sum,
                                            (float*)d_out);
}

// Round 7
// 4614.460 us; speedup vs baseline: 3.5950x; 1.0904x over previous
//
#include <hip/hip_runtime.h>
#include <stdint.h>

typedef __attribute__((ext_vector_type(4))) int i32x4;

static constexpr int BB = 256, TT = 64, NIN = 700, NKP = 768, HH = 2048, OO = 20;
static constexpr float THRESH_V = 0.3f;
static constexpr int NOBLK = 20;                 // o_dot blocks (bids 0..19)
static constexpr int NGEMM = 256;                // 4 m-tiles (M64) x 64 n-tiles (N32)
static constexpr int NIT_REC = 16, NIT = 28;     // 16 rec K-chunks (128B) + 12 x K-chunks (64B)

// ---------------- ws layout (bytes) ---- unchanged from validated round-5 ----
static constexpr size_t OFF_HMEM  = 0;           // 256*2048*4
static constexpr size_t OFF_SPK0  = 2097152;     // 256*2048*1 (i8)
static constexpr size_t OFF_OMEM  = 2621440;
static constexpr size_t OFF_OSPK  = 2641920;
static constexpr size_t OFF_OSUM  = 2662400;
static constexpr size_t ZERO_END  = 2682880;
static constexpr size_t OFF_SPK1  = 2682880;
static constexpr size_t OFF_ALPHA = 3207168;
static constexpr size_t OFF_WHHD  = 3207424;     // 4 planes x 2048*2048 i8
static constexpr size_t WHH_PLANE = 4194304;
static constexpr size_t OFF_WIHD  = 19984640;    // 4 planes x 2048*768 i8
static constexpr size_t WIH_PLANE = 1572864;
static constexpr size_t OFF_XD    = 26276096;    // 4 planes x 64*256*768 i8
static constexpr size_t XD_PLANE  = 12582912;
static constexpr size_t WS_NEED   = 76607744;

// ---------------- sync primitives ----------------
#define WAIT_VM6() asm volatile("s_waitcnt vmcnt(6)" ::: "memory")
#define WAIT_VM0() asm volatile("s_waitcnt vmcnt(0)" ::: "memory")
#define SCHED0()   __builtin_amdgcn_sched_barrier(0)

// ---------------- digit helpers (identical to validated round 5) ----------------
__device__ __forceinline__ void wdig(float w, double scale, signed char d[4]) {
    int q = (int)rint((double)w * scale);
    int t0 = (int)(signed char)(q & 0xFF); q = (q - t0) >> 8;
    int t1 = (int)(signed char)(q & 0xFF); q = (q - t1) >> 8;
    int t2 = (int)(signed char)(q & 0xFF); q = (q - t2) >> 8;
    d[0] = (signed char)t0; d[1] = (signed char)t1;
    d[2] = (signed char)t2; d[3] = (signed char)q;
}

// ---------------- LDS fragment reads ----------------
// rec tiles: [rows][128B], 16B slot XOR'd by (row&7)  (round-5/6 proven, 0 conflicts)
__device__ __forceinline__ i32x4 ld_rec(const uint8_t* base, int row, int sl) {
    return *reinterpret_cast<const i32x4*>(base + row * 128 + ((sl ^ (row & 7)) << 4));
}
// x tiles: [rows][64B], phys16Bslot = (s + row/2) & 3 -> 2-way max (free)
__device__ __forceinline__ i32x4 ld_x(const uint8_t* base, int row, int s) {
    int phys = (s + (row >> 1)) & 3;
    return *reinterpret_cast<const i32x4*>(base + row * 64 + (phys << 4));
}

__device__ __forceinline__ void gload(const uint8_t* src, uint8_t* dst) {
    __builtin_amdgcn_global_load_lds((const __attribute__((address_space(1))) void*)src,
                                     (__attribute__((address_space(3))) void*)dst, 16, 0, 0);
}

// ---------------- stage one 24KB chunk (6 gload_lds per wave, uniform) ----------------
// rec chunk: A = spk 64 rows x 128B @0 ; B = whh 4 planes x (32 rows x 128B) @8192+p*4096
__device__ __forceinline__ void stage_rec(uint8_t* buf, const int8_t* spk, const int8_t* whhd,
                                          int m0, int n0, int k0B, int wid, int lane) {
#pragma unroll
    for (int i = 0; i < 2; ++i) {                    // A: chunks {wid, wid+4}
        int c   = wid + i * 4;
        int row = c * 8 + (lane >> 3);               // 0..63
        int s   = (lane & 7) ^ (row & 7);            // logical slot for this phys position
        gload((const uint8_t*)spk + (size_t)(m0 + row) * HH + k0B + (s << 4),
              buf + c * 1024);
    }
#pragma unroll
    for (int sub = 0; sub < 4; ++sub) {              // B: wave wid owns plane wid
        int row = sub * 8 + (lane >> 3);             // j 0..31
        int s   = (lane & 7) ^ (row & 7);
        gload((const uint8_t*)whhd + (size_t)wid * WHH_PLANE +
              (size_t)(n0 + row) * HH + k0B + (s << 4),
              buf + 8192 + wid * 4096 + sub * 1024);
    }
}
// x chunk: A = xd 4 planes x (64 rows x 64B) @p*4096 ; B = wih 4 planes x (32 x 64B) @16384+p*2048
__device__ __forceinline__ void stage_x(uint8_t* buf, const int8_t* xd_t, const int8_t* wihd,
                                        int m0, int n0, int k0B, int wid, int lane) {
#pragma unroll
    for (int sub = 0; sub < 4; ++sub) {              // A: wave wid owns plane wid
        int row = sub * 16 + (lane >> 2);            // 0..63
        int s   = ((lane & 3) - (row >> 1)) & 3;     // inverse of read-side swizzle
        gload((const uint8_t*)xd_t + (size_t)wid * XD_PLANE +
              (size_t)(m0 + row) * NKP + k0B + (s << 4),
              buf + wid * 4096 + sub * 1024);
    }
#pragma unroll
    for (int i = 0; i < 2; ++i) {                    // B: chunks {wid, wid+4} of 8
        int cb  = wid + i * 4;
        int p   = cb >> 1, sub = cb & 1;
        int row = sub * 16 + (lane >> 2);            // j 0..31
        int s   = ((lane & 3) - (row >> 1)) & 3;
        gload((const uint8_t*)wihd + (size_t)p * WIH_PLANE +
              (size_t)(n0 + row) * NKP + k0B + (s << 4),
              buf + 16384 + p * 2048 + sub * 1024);
    }
}

// ---------------- MFMA phases ----------------
__device__ __forceinline__ void mfma_rec(const uint8_t* buf, int mw, int nw, int fr, int hi4,
                                         i32x4 aR[4][2]) {
#pragma unroll
    for (int ks = 0; ks < 2; ++ks) {
        int sl = ks * 4 + hi4;
        i32x4 a0 = ld_rec(buf, mw * 32 + fr,      sl);
        i32x4 a1 = ld_rec(buf, mw * 32 + 16 + fr, sl);
#pragma unroll
        for (int p = 0; p < 4; ++p) {
            i32x4 b = ld_rec(buf + 8192 + p * 4096, nw * 16 + fr, sl);
            aR[p][0] = __builtin_amdgcn_mfma_i32_16x16x64_i8(a0, b, aR[p][0], 0, 0, 0);
            aR[p][1] = __builtin_amdgcn_mfma_i32_16x16x64_i8(a1, b, aR[p][1], 0, 0, 0);
        }
    }
}
__device__ __forceinline__ void mfma_x(const uint8_t* buf, int mw, int nw, int fr, int hi4,
                                       i32x4 aX[5][2]) {
    i32x4 fa[4][2], fb[4];
#pragma unroll
    for (int p = 0; p < 4; ++p) {
        fa[p][0] = ld_x(buf + p * 4096, mw * 32 + fr,      hi4);
        fa[p][1] = ld_x(buf + p * 4096, mw * 32 + 16 + fr, hi4);
        fb[p]    = ld_x(buf + 16384 + p * 2048, nw * 16 + fr, hi4);
    }
#pragma unroll
    for (int a = 0; a < 4; ++a)
#pragma unroll
        for (int b = 0; b < 4; ++b) {
            if (a + b < 2) continue;                 // dropped terms ~2e-9 rms (validated)
            const int c = a + b - 2;
            aX[c][0] = __builtin_amdgcn_mfma_i32_16x16x64_i8(fa[a][0], fb[b], aX[c][0], 0, 0, 0);
            aX[c][1] = __builtin_amdgcn_mfma_i32_16x16x64_i8(fa[a][1], fb[b], aX[c][1], 0, 0, 0);
        }
}

// ---------------- conversion kernels (unchanged, validated) ----------------
__global__ __launch_bounds__(256) void conv_whh_i8(const float* __restrict__ W,
                                                   int8_t* __restrict__ p0, int8_t* __restrict__ p1,
                                                   int8_t* __restrict__ p2, int8_t* __restrict__ p3,
                                                   const float* __restrict__ tau_h,
                                                   const float* __restrict__ tau_o,
                                                   float* __restrict__ alpha) {
    int idx = blockIdx.x * 256 + threadIdx.x;
    if (idx == 0) {
        float qh = __fdiv_rn(-1.0f, tau_h[0]);
        float qo = __fdiv_rn(-1.0f, tau_o[0]);
        alpha[0] = (float)exp((double)qh);
        alpha[1] = (float)exp((double)qo);
    }
    float4 v = reinterpret_cast<const float4*>(W)[idx];
    signed char dx[4], dy[4], dz[4], dw[4];
    const double SC = 1073741824.0;  // 2^30
    wdig(v.x, SC, dx); wdig(v.y, SC, dy); wdig(v.z, SC, dz); wdig(v.w, SC, dw);
    reinterpret_cast<char4*>(p0)[idx] = make_char4(dx[0], dy[0], dz[0], dw[0]);
    reinterpret_cast<char4*>(p1)[idx] = make_char4(dx[1], dy[1], dz[1], dw[1]);
    reinterpret_cast<char4*>(p2)[idx] = make_char4(dx[2], dy[2], dz[2], dw[2]);
    reinterpret_cast<char4*>(p3)[idx] = make_char4(dx[3], dy[3], dz[3], dw[3]);
}

__global__ __launch_bounds__(256) void conv_wih_i8(const float* __restrict__ W,
                                                   int8_t* __restrict__ p0, int8_t* __restrict__ p1,
                                                   int8_t* __restrict__ p2, int8_t* __restrict__ p3) {
    int row = blockIdx.x;
    for (int i = threadIdx.x; i < NKP; i += 256) {
        float v = (i < NIN) ? W[(size_t)row * NIN + i] : 0.f;
        signed char d[4];
        wdig(v, 1073741824.0, d);        // 2^30
        size_t o = (size_t)row * NKP + i;
        p0[o] = d[0]; p1[o] = d[1]; p2[o] = d[2]; p3[o] = d[3];
    }
}

__global__ __launch_bounds__(256) void conv_x_i8(const float* __restrict__ in,
                                                 int8_t* __restrict__ p0, int8_t* __restrict__ p1,
                                                 int8_t* __restrict__ p2, int8_t* __restrict__ p3) {
    int blk = blockIdx.x;
    int t = blk >> 8, b = blk & 255;
    const float* src = in + ((size_t)b * TT + t) * NIN;   // input [B,T,N]
    size_t dst = ((size_t)t * BB + b) * NKP;              // digits [T,B,NKP]
    for (int i = threadIdx.x; i < NKP; i += 256) {
        float v = (i < NIN) ? src[i] : 0.f;
        signed char d[4];
        wdig(v, 16777216.0, d);          // 2^24
        p0[dst + i] = d[0]; p1[dst + i] = d[1]; p2[dst + i] = d[2]; p3[dst + i] = d[3];
    }
}

// ---------------- output-LIF: one thread per (b,o) dot, branchless f64 (validated) ----------------
__device__ __forceinline__ void o_dot(int gid, const int8_t* __restrict__ spk,
                                      const float* __restrict__ W_ho, const float* __restrict__ b_ho,
                                      float a_o, float* __restrict__ o_mem,
                                      float* __restrict__ o_spk, float* __restrict__ o_sum,
                                      float* __restrict__ out /*nullptr unless final*/) {
    int b = gid / OO, o = gid % OO;
    const int8_t* srow = spk  + (size_t)b * HH;
    const float*  wrow = W_ho + (size_t)o * HH;
    double a0 = 0.0, a1 = 0.0, a2 = 0.0, a3 = 0.0;
    for (int k = 0; k < HH; k += 8) {
        int2   s  = *reinterpret_cast<const int2*>(srow + k);
        float4 w0 = *reinterpret_cast<const float4*>(wrow + k);
        float4 w1 = *reinterpret_cast<const float4*>(wrow + k + 4);
        a0 += (s.x & 0x000000FF) ? (double)w0.x : 0.0;
        a1 += (s.x & 0x0000FF00) ? (double)w0.y : 0.0;
        a2 += (s.x & 0x00FF0000) ? (double)w0.z : 0.0;
        a3 += (s.x & 0xFF000000) ? (double)w0.w : 0.0;
        a0 += (s.y & 0x000000FF) ? (double)w1.x : 0.0;
        a1 += (s.y & 0x0000FF00) ? (double)w1.y : 0.0;
        a2 += (s.y & 0x00FF0000) ? (double)w1.z : 0.0;
        a3 += (s.y & 0xFF000000) ? (double)w1.w : 0.0;
    }
    float dot = (float)((a0 + a1) + (a2 + a3));
    size_t oo = (size_t)b * OO + o;
    float om = o_mem[oo], osp = o_spk[oo];
    float v = __fadd_rn(__fadd_rn(__fmul_rn(__fmul_rn(om, a_o), 1.f - osp), dot), b_ho[o]);
    float sn = (v > THRESH_V) ? 1.f : 0.f;
    o_mem[oo] = v;
    o_spk[oo] = sn;
    float s = __fadd_rn(o_sum[oo], sn);
    o_sum[oo] = s;
    if (out) out[oo] = __fmul_rn(s, 1.f / 64.f);
}

// ---------------- per-step fused kernel ----------------
__global__ __launch_bounds__(256, 2) void step_kernel(
    const int8_t* __restrict__ whhd, const int8_t* __restrict__ wihd,
    const int8_t* __restrict__ xd,
    const int8_t* __restrict__ spk_rd, int8_t* __restrict__ spk_wr,
    float* __restrict__ h_mem, const float* __restrict__ alpha,
    const float* __restrict__ b_ih, const float* __restrict__ b_hh,
    const float* __restrict__ W_ho, const float* __restrict__ b_ho,
    float* __restrict__ o_mem, float* __restrict__ o_spk, float* __restrict__ o_sum,
    int t) {
    // three statically-named 24KB buffers -> alias-analyzable, counted waits survive
    __shared__ __align__(16) uint8_t L0[24576];
    __shared__ __align__(16) uint8_t L1[24576];
    __shared__ __align__(16) uint8_t L2[24576];

    int bid = blockIdx.x;
    int tid = threadIdx.x;

    if (bid >= NOBLK) {
        int g = bid - NOBLK;                 // 0..255
        int lane = tid & 63, wid = tid >> 6;
        int m0 = (g >> 6) * 64;              // 4 m-tiles of 64 batches
        int n0 = (g & 63) * 32;              // 64 n-tiles; same-n blocks differ by 64 -> same XCD
        int mw = wid >> 1, nw = wid & 1;     // wave covers 32m x 16n
        int fr = lane & 15, hi4 = lane >> 4;

        const int8_t* xd_t = xd + (size_t)t * BB * NKP;

        i32x4 aR[4][2] = {};                 // rec digit accumulators [plane][msub]
        i32x4 aX[5][2] = {};                 // x digit-pair accumulators [a+b-2][msub]

        // prologue: 2 chunks in flight (12 loads/wave)
        stage_rec(L0, spk_rd, whhd, m0, n0, 0,   wid, lane);
        stage_rec(L1, spk_rd, whhd, m0, n0, 128, wid, lane);

#pragma unroll
        for (int h = 0; h < NIT; ++h) {
            if (h < NIT - 1) { WAIT_VM6(); } else { WAIT_VM0(); }   // buf[h] complete
            SCHED0();
            __builtin_amdgcn_s_barrier();    // all waves have buf[h]; reads of buf[h-1] done
            if (h + 2 < NIT) {               // overwrite buf[(h-1)%3] — safe after barrier
                uint8_t* nb = ((h + 2) % 3 == 0) ? L0 : ((h + 2) % 3 == 1) ? L1 : L2;
                if (h + 2 < NIT_REC)
                    stage_rec(nb, spk_rd, whhd, m0, n0, (h + 2) * 128, wid, lane);
                else
                    stage_x(nb, xd_t, wihd, m0, n0, (h + 2 - NIT_REC) * 64, wid, lane);
            }
            const uint8_t* cb = (h % 3 == 0) ? L0 : (h % 3 == 1) ? L1 : L2;
            __builtin_amdgcn_s_setprio(1);
            if (h < NIT_REC) mfma_rec(cb, mw, nw, fr, hi4, aR);
            else             mfma_x(cb, mw, nw, fr, hi4, aX);
            __builtin_amdgcn_s_setprio(0);
        }

        // ---- epilogue: LIF update, np's exact op order (identical to round 5) ----
        float a_h = alpha[0];
        int j  = n0 + nw * 16 + fr;
        int rq = hi4 * 4;
#pragma unroll
        for (int msub = 0; msub < 2; ++msub)
#pragma unroll
            for (int r = 0; r < 4; ++r) {
                int b = m0 + mw * 32 + msub * 16 + rq + r;
                size_t off = (size_t)b * HH + j;
                float recf = (float)((double)aR[3][msub][r] * 0x1p-6
                                   + (double)aR[2][msub][r] * 0x1p-14
                                   + (double)aR[1][msub][r] * 0x1p-22
                                   + (double)aR[0][msub][r] * 0x1p-30);
                double xp64 = (double)aX[4][msub][r] * 0x1p-6
                            + (double)aX[3][msub][r] * 0x1p-14
                            + (double)aX[2][msub][r] * 0x1p-22
                            + (double)aX[1][msub][r] * 0x1p-30
                            + (double)aX[0][msub][r] * 0x1p-38;
                float xpf = (float)xp64;
                float xpb = __fadd_rn(xpf, b_ih[j]);
                float hv  = h_mem[off];
                float keep = spk_rd[off] ? 0.f : 1.f;
                float v = __fadd_rn(__fmul_rn(__fmul_rn(hv, a_h), keep), xpb);
                v = __fadd_rn(v, recf);
                v = __fadd_rn(v, b_hh[j]);
                h_mem[off] = v;
                spk_wr[off] = (v > THRESH_V) ? (int8_t)1 : (int8_t)0;
            }
    } else {
        if (t == 0) return;                  // no step-(t-1) spikes yet
        int gid = bid * 256 + tid;           // 0..5119
        o_dot(gid, spk_rd, W_ho, b_ho, alpha[1], o_mem, o_spk, o_sum, nullptr);
    }
}

__global__ __launch_bounds__(256) void final_kernel(const int8_t* __restrict__ spk,
                                                    const float* __restrict__ W_ho,
                                                    const float* __restrict__ b_ho,
                                                    const float* __restrict__ alpha,
                                                    float* __restrict__ o_mem,
                                                    float* __restrict__ o_spk,
                                                    float* __restrict__ o_sum,
                                                    float* __restrict__ out) {
    int gid = blockIdx.x * 256 + threadIdx.x;
    o_dot(gid, spk, W_ho, b_ho, alpha[1], o_mem, o_spk, o_sum, out);
}

// ---------------- host ----------------
extern "C" void kernel_launch(void* const* d_in, const int* in_sizes, int n_in,
                              void* d_out, int out_size, void* d_ws, size_t ws_size,
                              hipStream_t stream) {
    const float* in    = (const float*)d_in[0];
    const float* W_ih  = (const float*)d_in[1];
    const float* b_ih  = (const float*)d_in[2];
    const float* W_hh  = (const float*)d_in[3];
    const float* b_hh  = (const float*)d_in[4];
    const float* W_ho  = (const float*)d_in[5];
    const float* b_ho  = (const float*)d_in[6];
    const float* tau_h = (const float*)d_in[7];
    const float* tau_o = (const float*)d_in[8];

    uint8_t* ws = (uint8_t*)d_ws;
    float*  h_mem = (float*)(ws + OFF_HMEM);
    int8_t* spk0  = (int8_t*)(ws + OFF_SPK0);
    float*  o_mem = (float*)(ws + OFF_OMEM);
    float*  o_spk = (float*)(ws + OFF_OSPK);
    float*  o_sum = (float*)(ws + OFF_OSUM);
    int8_t* spk1  = (int8_t*)(ws + OFF_SPK1);
    float*  alpha = (float*)(ws + OFF_ALPHA);
    int8_t* whhd  = (int8_t*)(ws + OFF_WHHD);
    int8_t* wihd  = (int8_t*)(ws + OFF_WIHD);
    int8_t* xd    = (int8_t*)(ws + OFF_XD);

    if (ws_size < WS_NEED) return;

    hipMemsetAsync(ws, 0, ZERO_END, stream);
    conv_whh_i8<<<4096, 256, 0, stream>>>(W_hh,
                                          whhd, whhd + WHH_PLANE, whhd + 2 * WHH_PLANE, whhd + 3 * WHH_PLANE,
                                          tau_h, tau_o, alpha);
    conv_wih_i8<<<2048, 256, 0, stream>>>(W_ih,
                                          wihd, wihd + WIH_PLANE, wihd + 2 * WIH_PLANE, wihd + 3 * WIH_PLANE);
    conv_x_i8<<<16384, 256, 0, stream>>>(in,
                                         xd, xd + XD_PLANE, xd + 2 * XD_PLANE, xd + 3 * XD_PLANE);

    for (int t = 0; t < TT; ++t) {
        const int8_t* srd = (t & 1) ? spk1 : spk0;
        int8_t*       swr = (t & 1) ? spk0 : spk1;
        step_kernel<<<NOBLK + NGEMM, 256, 0, stream>>>(whhd, wihd, xd, srd, swr, h_mem, alpha,
                                                       b_ih, b_hh, W_ho, b_ho,
                                                       o_mem, o_spk, o_sum, t);
    }
    final_kernel<<<NOBLK, 256, 0, stream>>>(spk0, W_ho, b_ho, alpha, o_mem, o_spk, o_sum,
                                            (float*)d_out);
}

// Round 8
// 1364.942 us; speedup vs baseline: 12.1535x; 3.3807x over previous
//
#include <hip/hip_runtime.h>
#include <stdint.h>

typedef __attribute__((ext_vector_type(4))) int i32x4;

static constexpr int BB = 256, TT = 64, NIN = 700, NKP = 768, HH = 2048, OO = 20;
static constexpr float THRESH_V = 0.3f;
static constexpr int NGEMM = 256;                // 4 m-tiles (M64) x 64 n-tiles (N32), bids 0..255
static constexpr int NOB   = 1280;               // o-dot blocks: 4 waves/block, 1 (b,o) pair per wave
static constexpr int NIT_REC = 16, NIT = 28;     // 16 rec K-chunks (128B) + 12 x K-chunks (64B)

// ---------------- ws layout (bytes) ---- unchanged from validated round-5 ----
static constexpr size_t OFF_HMEM  = 0;           // 256*2048*4
static constexpr size_t OFF_SPK0  = 2097152;     // 256*2048*1 (i8)
static constexpr size_t OFF_OMEM  = 2621440;
static constexpr size_t OFF_OSPK  = 2641920;
static constexpr size_t OFF_OSUM  = 2662400;
static constexpr size_t ZERO_END  = 2682880;
static constexpr size_t OFF_SPK1  = 2682880;
static constexpr size_t OFF_ALPHA = 3207168;
static constexpr size_t OFF_WHHD  = 3207424;     // 4 planes x 2048*2048 i8
static constexpr size_t WHH_PLANE = 4194304;
static constexpr size_t OFF_WIHD  = 19984640;    // 4 planes x 2048*768 i8
static constexpr size_t WIH_PLANE = 1572864;
static constexpr size_t OFF_XD    = 26276096;    // 4 planes x 64*256*768 i8
static constexpr size_t XD_PLANE  = 12582912;
static constexpr size_t WS_NEED   = 76607744;

// ---------------- sync primitives ----------------
#define WAIT_VM6() asm volatile("s_waitcnt vmcnt(6)" ::: "memory")
#define WAIT_VM0() asm volatile("s_waitcnt vmcnt(0)" ::: "memory")
#define SCHED0()   __builtin_amdgcn_sched_barrier(0)

// ---------------- digit helpers (identical to validated round 5) ----------------
__device__ __forceinline__ void wdig(float w, double scale, signed char d[4]) {
    int q = (int)rint((double)w * scale);
    int t0 = (int)(signed char)(q & 0xFF); q = (q - t0) >> 8;
    int t1 = (int)(signed char)(q & 0xFF); q = (q - t1) >> 8;
    int t2 = (int)(signed char)(q & 0xFF); q = (q - t2) >> 8;
    d[0] = (signed char)t0; d[1] = (signed char)t1;
    d[2] = (signed char)t2; d[3] = (signed char)q;
}

// ---------------- LDS fragment reads ----------------
// rec tiles: [rows][128B], 16B slot XOR'd by (row&7)  (round-5/6/7 proven, 0 conflicts)
__device__ __forceinline__ i32x4 ld_rec(const uint8_t* base, int row, int sl) {
    return *reinterpret_cast<const i32x4*>(base + row * 128 + ((sl ^ (row & 7)) << 4));
}
// x tiles: [rows][64B], phys16Bslot = (s + row/2) & 3 -> 2-way max (free)
__device__ __forceinline__ i32x4 ld_x(const uint8_t* base, int row, int s) {
    int phys = (s + (row >> 1)) & 3;
    return *reinterpret_cast<const i32x4*>(base + row * 64 + (phys << 4));
}

__device__ __forceinline__ void gload(const uint8_t* src, uint8_t* dst) {
    __builtin_amdgcn_global_load_lds((const __attribute__((address_space(1))) void*)src,
                                     (__attribute__((address_space(3))) void*)dst, 16, 0, 0);
}

// ---------------- stage one 24KB chunk (6 gload_lds per wave, uniform) ----------------
// rec chunk: A = spk 64 rows x 128B @0 ; B = whh 4 planes x (32 rows x 128B) @8192+p*4096
__device__ __forceinline__ void stage_rec(uint8_t* buf, const int8_t* spk, const int8_t* whhd,
                                          int m0, int n0, int k0B, int wid, int lane) {
#pragma unroll
    for (int i = 0; i < 2; ++i) {                    // A: chunks {wid, wid+4}
        int c   = wid + i * 4;
        int row = c * 8 + (lane >> 3);               // 0..63
        int s   = (lane & 7) ^ (row & 7);            // logical slot for this phys position
        gload((const uint8_t*)spk + (size_t)(m0 + row) * HH + k0B + (s << 4),
              buf + c * 1024);
    }
#pragma unroll
    for (int sub = 0; sub < 4; ++sub) {              // B: wave wid owns plane wid
        int row = sub * 8 + (lane >> 3);             // j 0..31
        int s   = (lane & 7) ^ (row & 7);
        gload((const uint8_t*)whhd + (size_t)wid * WHH_PLANE +
              (size_t)(n0 + row) * HH + k0B + (s << 4),
              buf + 8192 + wid * 4096 + sub * 1024);
    }
}
// x chunk: A = xd 4 planes x (64 rows x 64B) @p*4096 ; B = wih 4 planes x (32 x 64B) @16384+p*2048
__device__ __forceinline__ void stage_x(uint8_t* buf, const int8_t* xd_t, const int8_t* wihd,
                                        int m0, int n0, int k0B, int wid, int lane) {
#pragma unroll
    for (int sub = 0; sub < 4; ++sub) {              // A: wave wid owns plane wid
        int row = sub * 16 + (lane >> 2);            // 0..63
        int s   = ((lane & 3) - (row >> 1)) & 3;     // inverse of read-side swizzle
        gload((const uint8_t*)xd_t + (size_t)wid * XD_PLANE +
              (size_t)(m0 + row) * NKP + k0B + (s << 4),
              buf + wid * 4096 + sub * 1024);
    }
#pragma unroll
    for (int i = 0; i < 2; ++i) {                    // B: chunks {wid, wid+4} of 8
        int cb  = wid + i * 4;
        int p   = cb >> 1, sub = cb & 1;
        int row = sub * 16 + (lane >> 2);            // j 0..31
        int s   = ((lane & 3) - (row >> 1)) & 3;
        gload((const uint8_t*)wihd + (size_t)p * WIH_PLANE +
              (size_t)(n0 + row) * NKP + k0B + (s << 4),
              buf + 16384 + p * 2048 + sub * 1024);
    }
}

// ---------------- MFMA phases ----------------
__device__ __forceinline__ void mfma_rec(const uint8_t* buf, int mw, int nw, int fr, int hi4,
                                         i32x4 aR[4][2]) {
#pragma unroll
    for (int ks = 0; ks < 2; ++ks) {
        int sl = ks * 4 + hi4;
        i32x4 a0 = ld_rec(buf, mw * 32 + fr,      sl);
        i32x4 a1 = ld_rec(buf, mw * 32 + 16 + fr, sl);
#pragma unroll
        for (int p = 0; p < 4; ++p) {
            i32x4 b = ld_rec(buf + 8192 + p * 4096, nw * 16 + fr, sl);
            aR[p][0] = __builtin_amdgcn_mfma_i32_16x16x64_i8(a0, b, aR[p][0], 0, 0, 0);
            aR[p][1] = __builtin_amdgcn_mfma_i32_16x16x64_i8(a1, b, aR[p][1], 0, 0, 0);
        }
    }
}
__device__ __forceinline__ void mfma_x(const uint8_t* buf, int mw, int nw, int fr, int hi4,
                                       i32x4 aX[5][2]) {
    i32x4 fa[4][2], fb[4];
#pragma unroll
    for (int p = 0; p < 4; ++p) {
        fa[p][0] = ld_x(buf + p * 4096, mw * 32 + fr,      hi4);
        fa[p][1] = ld_x(buf + p * 4096, mw * 32 + 16 + fr, hi4);
        fb[p]    = ld_x(buf + 16384 + p * 2048, nw * 16 + fr, hi4);
    }
#pragma unroll
    for (int a = 0; a < 4; ++a)
#pragma unroll
        for (int b = 0; b < 4; ++b) {
            if (a + b < 2) continue;                 // dropped terms ~2e-9 rms (validated)
            const int c = a + b - 2;
            aX[c][0] = __builtin_amdgcn_mfma_i32_16x16x64_i8(fa[a][0], fb[b], aX[c][0], 0, 0, 0);
            aX[c][1] = __builtin_amdgcn_mfma_i32_16x16x64_i8(fa[a][1], fb[b], aX[c][1], 0, 0, 0);
        }
}

// ---------------- conversion kernels (unchanged, validated) ----------------
__global__ __launch_bounds__(256) void conv_whh_i8(const float* __restrict__ W,
                                                   int8_t* __restrict__ p0, int8_t* __restrict__ p1,
                                                   int8_t* __restrict__ p2, int8_t* __restrict__ p3,
                                                   const float* __restrict__ tau_h,
                                                   const float* __restrict__ tau_o,
                                                   float* __restrict__ alpha) {
    int idx = blockIdx.x * 256 + threadIdx.x;
    if (idx == 0) {
        float qh = __fdiv_rn(-1.0f, tau_h[0]);
        float qo = __fdiv_rn(-1.0f, tau_o[0]);
        alpha[0] = (float)exp((double)qh);
        alpha[1] = (float)exp((double)qo);
    }
    float4 v = reinterpret_cast<const float4*>(W)[idx];
    signed char dx[4], dy[4], dz[4], dw[4];
    const double SC = 1073741824.0;  // 2^30
    wdig(v.x, SC, dx); wdig(v.y, SC, dy); wdig(v.z, SC, dz); wdig(v.w, SC, dw);
    reinterpret_cast<char4*>(p0)[idx] = make_char4(dx[0], dy[0], dz[0], dw[0]);
    reinterpret_cast<char4*>(p1)[idx] = make_char4(dx[1], dy[1], dz[1], dw[1]);
    reinterpret_cast<char4*>(p2)[idx] = make_char4(dx[2], dy[2], dz[2], dw[2]);
    reinterpret_cast<char4*>(p3)[idx] = make_char4(dx[3], dy[3], dz[3], dw[3]);
}

__global__ __launch_bounds__(256) void conv_wih_i8(const float* __restrict__ W,
                                                   int8_t* __restrict__ p0, int8_t* __restrict__ p1,
                                                   int8_t* __restrict__ p2, int8_t* __restrict__ p3) {
    int row = blockIdx.x;
    for (int i = threadIdx.x; i < NKP; i += 256) {
        float v = (i < NIN) ? W[(size_t)row * NIN + i] : 0.f;
        signed char d[4];
        wdig(v, 1073741824.0, d);        // 2^30
        size_t o = (size_t)row * NKP + i;
        p0[o] = d[0]; p1[o] = d[1]; p2[o] = d[2]; p3[o] = d[3];
    }
}

__global__ __launch_bounds__(256) void conv_x_i8(const float* __restrict__ in,
                                                 int8_t* __restrict__ p0, int8_t* __restrict__ p1,
                                                 int8_t* __restrict__ p2, int8_t* __restrict__ p3) {
    int blk = blockIdx.x;
    int t = blk >> 8, b = blk & 255;
    const float* src = in + ((size_t)b * TT + t) * NIN;   // input [B,T,N]
    size_t dst = ((size_t)t * BB + b) * NKP;              // digits [T,B,NKP]
    for (int i = threadIdx.x; i < NKP; i += 256) {
        float v = (i < NIN) ? src[i] : 0.f;
        signed char d[4];
        wdig(v, 16777216.0, d);          // 2^24
        p0[dst + i] = d[0]; p1[dst + i] = d[1]; p2[dst + i] = d[2]; p3[dst + i] = d[3];
    }
}

// ---------------- output-LIF: one WAVE per (b,o) dot ----------------
// Lane l sums k in [l*32, l*32+32) in f64, then 6-step f64 butterfly reduce.
// Single f32 rounding at the end -> same value as the validated serial f64 sum
// (f64 reassociation noise ~1e-16 rel, invisible at f32 precision).
__device__ __forceinline__ void o_dot_wave(int pair, int lane, const int8_t* __restrict__ spk,
                                           const float* __restrict__ W_ho,
                                           const float* __restrict__ b_ho,
                                           float a_o, float* __restrict__ o_mem,
                                           float* __restrict__ o_spk, float* __restrict__ o_sum,
                                           float* __restrict__ out /*nullptr unless final*/) {
    int b = pair / OO, o = pair % OO;
    const int8_t* srow = spk  + (size_t)b * HH + lane * 32;
    const float*  wrow = W_ho + (size_t)o * HH + lane * 32;
    int4 s0 = *reinterpret_cast<const int4*>(srow);
    int4 s1 = *reinterpret_cast<const int4*>(srow + 16);
    int sw[8] = {s0.x, s0.y, s0.z, s0.w, s1.x, s1.y, s1.z, s1.w};
    double acc = 0.0;
#pragma unroll
    for (int q = 0; q < 8; ++q) {
        float4 w = *reinterpret_cast<const float4*>(wrow + q * 4);
        int sv = sw[q];
        acc += (sv & 0x000000FF) ? (double)w.x : 0.0;
        acc += (sv & 0x0000FF00) ? (double)w.y : 0.0;
        acc += (sv & 0x00FF0000) ? (double)w.z : 0.0;
        acc += (sv & 0xFF000000) ? (double)w.w : 0.0;
    }
#pragma unroll
    for (int off = 32; off >= 1; off >>= 1)
        acc += __shfl_xor(acc, off, 64);
    if (lane == 0) {
        float dot = (float)acc;
        size_t oo = (size_t)b * OO + o;
        float om = o_mem[oo], osp = o_spk[oo];
        // np order: ((o_mem*alpha)*(1-o_spike) + dot) + b_ho
        float v = __fadd_rn(__fadd_rn(__fmul_rn(__fmul_rn(om, a_o), 1.f - osp), dot), b_ho[o]);
        float sn = (v > THRESH_V) ? 1.f : 0.f;
        o_mem[oo] = v;
        o_spk[oo] = sn;
        float s = __fadd_rn(o_sum[oo], sn);
        o_sum[oo] = s;
        if (out) out[oo] = __fmul_rn(s, 1.f / 64.f);
    }
}

// ---------------- per-step fused kernel ----------------
__global__ __launch_bounds__(256, 2) void step_kernel(
    const int8_t* __restrict__ whhd, const int8_t* __restrict__ wihd,
    const int8_t* __restrict__ xd,
    const int8_t* __restrict__ spk_rd, int8_t* __restrict__ spk_wr,
    float* __restrict__ h_mem, const float* __restrict__ alpha,
    const float* __restrict__ b_ih, const float* __restrict__ b_hh,
    const float* __restrict__ W_ho, const float* __restrict__ b_ho,
    float* __restrict__ o_mem, float* __restrict__ o_spk, float* __restrict__ o_sum,
    int t) {
    // three statically-named 24KB buffers -> alias-analyzable, counted waits survive
    __shared__ __align__(16) uint8_t L0[24576];
    __shared__ __align__(16) uint8_t L1[24576];
    __shared__ __align__(16) uint8_t L2[24576];

    int bid = blockIdx.x;
    int tid = threadIdx.x;
    int lane = tid & 63, wid = tid >> 6;

    if (bid < NGEMM) {
        int g = bid;                         // 0..255
        int m0 = (g >> 6) * 64;              // 4 m-tiles of 64 batches
        int n0 = (g & 63) * 32;              // 64 n-tiles; same-n blocks differ by 64 -> same XCD
        int mw = wid >> 1, nw = wid & 1;     // wave covers 32m x 16n
        int fr = lane & 15, hi4 = lane >> 4;

        const int8_t* xd_t = xd + (size_t)t * BB * NKP;

        i32x4 aR[4][2] = {};                 // rec digit accumulators [plane][msub]
        i32x4 aX[5][2] = {};                 // x digit-pair accumulators [a+b-2][msub]

        // prologue: 2 chunks in flight (12 loads/wave)
        stage_rec(L0, spk_rd, whhd, m0, n0, 0,   wid, lane);
        stage_rec(L1, spk_rd, whhd, m0, n0, 128, wid, lane);

#pragma unroll
        for (int h = 0; h < NIT; ++h) {
            if (h < NIT - 1) { WAIT_VM6(); } else { WAIT_VM0(); }   // buf[h] complete
            SCHED0();
            __builtin_amdgcn_s_barrier();    // all waves have buf[h]; reads of buf[h-1] done
            if (h + 2 < NIT) {               // overwrite buf[(h-1)%3] — safe after barrier
                uint8_t* nb = ((h + 2) % 3 == 0) ? L0 : ((h + 2) % 3 == 1) ? L1 : L2;
                if (h + 2 < NIT_REC)
                    stage_rec(nb, spk_rd, whhd, m0, n0, (h + 2) * 128, wid, lane);
                else
                    stage_x(nb, xd_t, wihd, m0, n0, (h + 2 - NIT_REC) * 64, wid, lane);
            }
            const uint8_t* cb = (h % 3 == 0) ? L0 : (h % 3 == 1) ? L1 : L2;
            __builtin_amdgcn_s_setprio(1);
            if (h < NIT_REC) mfma_rec(cb, mw, nw, fr, hi4, aR);
            else             mfma_x(cb, mw, nw, fr, hi4, aX);
            __builtin_amdgcn_s_setprio(0);
        }

        // ---- epilogue: LIF update, np's exact op order (identical to round 5) ----
        float a_h = alpha[0];
        int j  = n0 + nw * 16 + fr;
        int rq = hi4 * 4;
#pragma unroll
        for (int msub = 0; msub < 2; ++msub)
#pragma unroll
            for (int r = 0; r < 4; ++r) {
                int b = m0 + mw * 32 + msub * 16 + rq + r;
                size_t off = (size_t)b * HH + j;
                float recf = (float)((double)aR[3][msub][r] * 0x1p-6
                                   + (double)aR[2][msub][r] * 0x1p-14
                                   + (double)aR[1][msub][r] * 0x1p-22
                                   + (double)aR[0][msub][r] * 0x1p-30);
                double xp64 = (double)aX[4][msub][r] * 0x1p-6
                            + (double)aX[3][msub][r] * 0x1p-14
                            + (double)aX[2][msub][r] * 0x1p-22
                            + (double)aX[1][msub][r] * 0x1p-30
                            + (double)aX[0][msub][r] * 0x1p-38;
                float xpf = (float)xp64;
                float xpb = __fadd_rn(xpf, b_ih[j]);
                float hv  = h_mem[off];
                float keep = spk_rd[off] ? 0.f : 1.f;
                float v = __fadd_rn(__fmul_rn(__fmul_rn(hv, a_h), keep), xpb);
                v = __fadd_rn(v, recf);
                v = __fadd_rn(v, b_hh[j]);
                h_mem[off] = v;
                spk_wr[off] = (v > THRESH_V) ? (int8_t)1 : (int8_t)0;
            }
    } else {
        if (t == 0) return;                  // no step-(t-1) spikes yet
        int pair = (bid - NGEMM) * 4 + wid;  // 0..5119
        o_dot_wave(pair, lane, spk_rd, W_ho, b_ho, alpha[1], o_mem, o_spk, o_sum, nullptr);
    }
}

__global__ __launch_bounds__(256) void final_kernel(const int8_t* __restrict__ spk,
                                                    const float* __restrict__ W_ho,
                                                    const float* __restrict__ b_ho,
                                                    const float* __restrict__ alpha,
                                                    float* __restrict__ o_mem,
                                                    float* __restrict__ o_spk,
                                                    float* __restrict__ o_sum,
                                                    float* __restrict__ out) {
    int lane = threadIdx.x & 63, wid = threadIdx.x >> 6;
    int pair = blockIdx.x * 4 + wid;         // 0..5119
    o_dot_wave(pair, lane, spk, W_ho, b_ho, alpha[1], o_mem, o_spk, o_sum, out);
}

// ---------------- host ----------------
extern "C" void kernel_launch(void* const* d_in, const int* in_sizes, int n_in,
                              void* d_out, int out_size, void* d_ws, size_t ws_size,
                              hipStream_t stream) {
    const float* in    = (const float*)d_in[0];
    const float* W_ih  = (const float*)d_in[1];
    const float* b_ih  = (const float*)d_in[2];
    const float* W_hh  = (const float*)d_in[3];
    const float* b_hh  = (const float*)d_in[4];
    const float* W_ho  = (const float*)d_in[5];
    const float* b_ho  = (const float*)d_in[6];
    const float* tau_h = (const float*)d_in[7];
    const float* tau_o = (const float*)d_in[8];

    uint8_t* ws = (uint8_t*)d_ws;
    float*  h_mem = (float*)(ws + OFF_HMEM);
    int8_t* spk0  = (int8_t*)(ws + OFF_SPK0);
    float*  o_mem = (float*)(ws + OFF_OMEM);
    float*  o_spk = (float*)(ws + OFF_OSPK);
    float*  o_sum = (float*)(ws + OFF_OSUM);
    int8_t* spk1  = (int8_t*)(ws + OFF_SPK1);
    float*  alpha = (float*)(ws + OFF_ALPHA);
    int8_t* whhd  = (int8_t*)(ws + OFF_WHHD);
    int8_t* wihd  = (int8_t*)(ws + OFF_WIHD);
    int8_t* xd    = (int8_t*)(ws + OFF_XD);

    if (ws_size < WS_NEED) return;

    hipMemsetAsync(ws, 0, ZERO_END, stream);
    conv_whh_i8<<<4096, 256, 0, stream>>>(W_hh,
                                          whhd, whhd + WHH_PLANE, whhd + 2 * WHH_PLANE, whhd + 3 * WHH_PLANE,
                                          tau_h, tau_o, alpha);
    conv_wih_i8<<<2048, 256, 0, stream>>>(W_ih,
                                          wihd, wihd + WIH_PLANE, wihd + 2 * WIH_PLANE, wihd + 3 * WIH_PLANE);
    conv_x_i8<<<16384, 256, 0, stream>>>(in,
                                         xd, xd + XD_PLANE, xd + 2 * XD_PLANE, xd + 3 * XD_PLANE);

    for (int t = 0; t < TT; ++t) {
        const int8_t* srd = (t & 1) ? spk1 : spk0;
        int8_t*       swr = (t & 1) ? spk0 : spk1;
        step_kernel<<<NGEMM + NOB, 256, 0, stream>>>(whhd, wihd, xd, srd, swr, h_mem, alpha,
                                                     b_ih, b_hh, W_ho, b_ho,
                                                     o_mem, o_spk, o_sum, t);
    }
    final_kernel<<<NOB, 256, 0, stream>>>(spk0, W_ho, b_ho, alpha, o_mem, o_spk, o_sum,
                                          (float*)d_out);
}